// Round 6
// baseline (1369.526 us; speedup 1.0000x reference)
//
#include <hip/hip_runtime.h>
#include <math.h>

// MoE forward, MI355X. Round 6: R5 design with the LDS OOB fixed
// (Bs was declared half-size: 16*64*KBLK/2 -> waves 8..15 DMA'd past the
// static LDS allocation -> memory-violation abort).
// Barrier-free per-wave K-loop: each wave stages & consumes its own B cols
// via global_load_lds (dbuf, vmcnt-paced); A frags per-lane from bf16 xb.
// B=32768 D=1200 E=16 H=1024 O=1 K=4.  d_out = [ y (32768 f32) | loss (1 f32) ]
//
// ws layout:
//   [0      , 4 MiB)   bucket_row [E][B] int ; bucket_gate [E][B] f32
//   [4 MiB +0)         cnt[16], +64 imp[16], +128 load[16]
//   [4 MiB +1 KiB)     Wp  bf16 [E][H][DP]  (~38 MiB)  -- ALIASED before pack_w1 by gate scratch
//   [~42 MiB)          xb  bf16 [B][D] (+pad)          -- only if ws_size allows (else MODE 0)

#define B_SZ   32768
#define D_SZ   1200
#define DP     1216
#define E_SZ   16
#define H_SZ   1024
#define LN_EPS 1e-5f
#define BM     64
#define KBLK   32
#define NSTEP  (DP / KBLK)     // 38
#define NBG    512
#define GR     64

typedef __attribute__((ext_vector_type(8))) short  short8;
typedef __attribute__((ext_vector_type(4))) float  f32x4;

__device__ __forceinline__ unsigned short f2bf(float f) {   // RNE f32->bf16
    unsigned u = __float_as_uint(f);
    unsigned r = u + 0x7FFFu + ((u >> 16) & 1u);
    return (unsigned short)(r >> 16);
}

__device__ __forceinline__ void gload_lds16(const void* g, void* l) {
    __builtin_amdgcn_global_load_lds(
        (const __attribute__((address_space(1))) void*)g,
        (__attribute__((address_space(3))) void*)l, 16, 0, 0);
}

// ------------------------------------------------------- gate A: logits ----
__global__ __launch_bounds__(256)
void gate_a(const float* __restrict__ x, const float* __restrict__ wg,
            unsigned short* __restrict__ xb,
            unsigned* __restrict__ tk_pack, float* __restrict__ gates4,
            unsigned short* __restrict__ lpos4,
            unsigned* __restrict__ hist_g, float* __restrict__ bimp_g)
{
    __shared__ int   hist[E_SZ];
    __shared__ float bimp[E_SZ];
    if (threadIdx.x < E_SZ) { hist[threadIdx.x] = 0; bimp[threadIdx.x] = 0.f; }
    __syncthreads();

    const int lane = threadIdx.x & 63;
    const int w    = threadIdx.x >> 6;        // 0..3
    const int rb   = blockIdx.x * GR;

    for (int it = 0; it < GR / 4; ++it) {
        const int row = rb + it * 4 + w;
        float acc[E_SZ];
#pragma unroll
        for (int e = 0; e < E_SZ; ++e) acc[e] = 0.f;

        const float* xr = x + (size_t)row * D_SZ;
        for (int d = lane; d < D_SZ; d += 64) {
            const float xv = xr[d];
            if (xb) xb[(size_t)row * D_SZ + d] = f2bf(xv);   // fold x->bf16 here
            const float4* w4 = (const float4*)(wg + (size_t)d * E_SZ);
            const float4 a = w4[0], b = w4[1], c = w4[2], dd = w4[3];
            acc[0]  += xv * a.x;  acc[1]  += xv * a.y;
            acc[2]  += xv * a.z;  acc[3]  += xv * a.w;
            acc[4]  += xv * b.x;  acc[5]  += xv * b.y;
            acc[6]  += xv * b.z;  acc[7]  += xv * b.w;
            acc[8]  += xv * c.x;  acc[9]  += xv * c.y;
            acc[10] += xv * c.z;  acc[11] += xv * c.w;
            acc[12] += xv * dd.x; acc[13] += xv * dd.y;
            acc[14] += xv * dd.z; acc[15] += xv * dd.w;
        }
#pragma unroll
        for (int e = 0; e < E_SZ; ++e) {
            float v = acc[e];
            v += __shfl_xor(v, 1);  v += __shfl_xor(v, 2);
            v += __shfl_xor(v, 4);  v += __shfl_xor(v, 8);
            v += __shfl_xor(v, 16); v += __shfl_xor(v, 32);
            acc[e] = v;
        }
        if (lane == 0) {
            float mx = acc[0];
#pragma unroll
            for (int e = 1; e < E_SZ; ++e) mx = fmaxf(mx, acc[e]);
            float p[E_SZ]; float s = 0.f;
#pragma unroll
            for (int e = 0; e < E_SZ; ++e) { p[e] = expf(acc[e] - mx); s += p[e]; }
            const float inv = 1.f / s;

            unsigned msk = 0; int idx[4]; float val[4]; float gsum = 0.f;
#pragma unroll
            for (int tsel = 0; tsel < 4; ++tsel) {
                float bv = -1.f; int bi = 0;
#pragma unroll
                for (int e = 0; e < E_SZ; ++e) {
                    const bool ok = !((msk >> e) & 1u) && (p[e] > bv);
                    bv = ok ? p[e] : bv; bi = ok ? e : bi;
                }
                msk |= 1u << bi;
                idx[tsel] = bi; val[tsel] = bv * inv; gsum += bv * inv;
            }
            const float denom = gsum + 1e-6f;
            unsigned tkp = 0;
#pragma unroll
            for (int tsel = 0; tsel < 4; ++tsel) {
                const float g = val[tsel] / denom;
                const int e = idx[tsel];
                const int lp = atomicAdd(&hist[e], 1);    // LDS atomic
                atomicAdd(&bimp[e], g);
                tkp |= (unsigned)e << (8 * tsel);
                gates4[row * 4 + tsel] = g;
                lpos4[row * 4 + tsel]  = (unsigned short)lp;
            }
            tk_pack[row] = tkp;
        }
    }
    __syncthreads();
    if (threadIdx.x < E_SZ) {
        hist_g[blockIdx.x * E_SZ + threadIdx.x] = (unsigned)hist[threadIdx.x];
        bimp_g[blockIdx.x * E_SZ + threadIdx.x] = bimp[threadIdx.x];
    }
}

// ------------------------------------- gate B: prefix scan + cnt + loss ----
__global__ __launch_bounds__(1024)
void gate_b(const unsigned* __restrict__ hist_g, const float* __restrict__ bimp_g,
            unsigned* __restrict__ base_g, int* __restrict__ cnt,
            float* __restrict__ imp, int* __restrict__ loadc,
            float* __restrict__ loss_out)
{
    __shared__ unsigned hh[NBG * E_SZ];   // 32 KiB
    __shared__ float    bb[NBG * E_SZ];   // 32 KiB
    __shared__ float    s_i[E_SZ], s_c[E_SZ];
    const int t = threadIdx.x;
    for (int i = t; i < NBG * E_SZ; i += 1024) { hh[i] = hist_g[i]; bb[i] = bimp_g[i]; }
    __syncthreads();
    if (t < E_SZ) {
        unsigned run = 0; float ri = 0.f;
        for (int b = 0; b < NBG; ++b) {
            base_g[b * E_SZ + t] = run;           // store: no latency stall
            run += hh[b * E_SZ + t];
            ri  += bb[b * E_SZ + t];
        }
        cnt[t] = (int)run; imp[t] = ri; loadc[t] = (int)run;
        s_i[t] = ri; s_c[t] = (float)run;
    }
    __syncthreads();
    if (t == 0) {
        float mi = 0.f, ml = 0.f;
        for (int e = 0; e < E_SZ; ++e) { mi += s_i[e]; ml += s_c[e]; }
        mi *= (1.f / E_SZ); ml *= (1.f / E_SZ);
        float vi = 0.f, vl = 0.f;
        for (int e = 0; e < E_SZ; ++e) {
            const float di = s_i[e] - mi; vi += di * di;
            const float dl = s_c[e] - ml; vl += dl * dl;
        }
        vi *= (1.f / (E_SZ - 1)); vl *= (1.f / (E_SZ - 1));
        *loss_out = 0.5f * (vi / (mi * mi + 1e-10f) + vl / (ml * ml + 1e-10f));
    }
}

// ------------------------------------------------- gate C: bucket scatter ---
__global__ __launch_bounds__(256)
void gate_c(const unsigned* __restrict__ tk_pack, const float* __restrict__ gates4,
            const unsigned short* __restrict__ lpos4, const unsigned* __restrict__ base_g,
            int* __restrict__ bucket_row, float* __restrict__ bucket_gate)
{
    const int t   = threadIdx.x;
    const int row = blockIdx.x * GR + (t >> 2);
    const int j   = t & 3;
    const unsigned tkp = tk_pack[row];
    const int e = (int)((tkp >> (8 * j)) & 0xffu);
    const unsigned dst = base_g[blockIdx.x * E_SZ + e] + (unsigned)lpos4[row * 4 + j];
    bucket_row[e * B_SZ + dst]  = row;
    bucket_gate[e * B_SZ + dst] = gates4[row * 4 + j];
}

// ------------------------------------------------ W1 transpose-pack (bf16) --
__global__ __launch_bounds__(256)
void pack_w1(const float* __restrict__ W1, unsigned short* __restrict__ Wp)
{
    __shared__ float tile[32][33];
    const int e  = blockIdx.z;
    const int d0 = blockIdx.x * 32;
    const int h0 = blockIdx.y * 32;
    const int tx = threadIdx.x & 31, ty = threadIdx.x >> 5;

    const float* W1e = W1 + (size_t)e * D_SZ * H_SZ;
#pragma unroll
    for (int i = 0; i < 4; ++i) {
        const int d = d0 + ty + i * 8;
        tile[ty + i * 8][tx] = (d < D_SZ) ? W1e[(size_t)d * H_SZ + h0 + tx] : 0.f;
    }
    __syncthreads();
    unsigned short* WpE = Wp + (size_t)e * H_SZ * DP;
#pragma unroll
    for (int i = 0; i < 4; ++i) {
        const int h = h0 + ty + i * 8;
        WpE[(size_t)h * DP + d0 + tx] = f2bf(tile[tx][ty + i * 8]);
    }
}

// --------------------------------------------------- grouped expert pass ----
// grid (512, 16), 1024 threads (16 waves). Block: 64 rows x H=1024.
// NO barriers in K-loop: wave w stages AND consumes cols [w*64, w*64+64)
// (per-wave dbuf, global_load_lds, vmcnt(0) with full-step prefetch distance).
// A frags: per-lane 16B dwordx4 gathers (MODE 1: bf16 xb; MODE 0: f32 x + cvt).
template<int MODE>
__global__ __launch_bounds__(1024, 4)
void expert_kernel(const float* __restrict__ x, const unsigned short* __restrict__ xb,
                   const unsigned short* __restrict__ Wp,
                   const float* __restrict__ b1, const float* __restrict__ gamma,
                   const float* __restrict__ beta, const float* __restrict__ W2,
                   const float* __restrict__ b2,
                   const int* __restrict__ bucket_row,
                   const float* __restrict__ bucket_gate,
                   const int* __restrict__ cnt, float* __restrict__ y)
{
    const int e   = blockIdx.y;
    const int n_e = cnt[e];
    const int r0  = blockIdx.x * BM;
    if (r0 >= n_e) return;

    // Per-wave region: 64 cols x KBLK k = 2048 bf16 = 4 KiB; 16 waves = 64 KiB/buffer.
    __shared__ unsigned short Bs[2][16 * 64 * KBLK];  // 2 x 64 KiB  (R5 bug: had /2)
    __shared__ float red[16][BM][2];                  // 8 KiB
    __shared__ float ln_m[BM], ln_r[BM];
    __shared__ int   srow[BM];
    __shared__ float sgate[BM];

    const int t   = threadIdx.x;
    const int w   = t >> 6;
    const int l   = t & 63;
    const int l15 = l & 15;
    const int lg  = l >> 4;

    if (t < BM) {
        const int i = r0 + t;
        srow[t]  = (i < n_e) ? bucket_row[e * B_SZ + i] : -1;
        sgate[t] = (i < n_e) ? bucket_gate[e * B_SZ + i] : 0.f;
    }
    __syncthreads();

    // A row base pointers (4 per lane, one per m-frag)
    const unsigned short* pA[4];
    const float*          pAx[4];
#pragma unroll
    for (int m = 0; m < 4; ++m) {
        int rr = srow[m * 16 + l15]; rr = (rr >= 0) ? rr : 0;
        if (MODE) pA[m]  = xb + (size_t)rr * D_SZ + lg * 8;
        else      pAx[m] = x  + (size_t)rr * D_SZ + lg * 8;
    }

    const unsigned short* WpE = Wp + (size_t)e * H_SZ * DP;
    const int bn0 = w * 64;
    unsigned short* Bw0 = &Bs[0][w * 2048];
    unsigned short* Bw1 = &Bs[1][w * 2048];
    const unsigned short* bsrc = WpE + (size_t)(bn0 + (l >> 2)) * DP + (l & 3) * 8;

    f32x4 acc[16];
#pragma unroll
    for (int i = 0; i < 16; ++i) acc[i] = {0.f, 0.f, 0.f, 0.f};

    // prologue: B(k=0) -> Bw0
#pragma unroll
    for (int i = 0; i < 4; ++i)
        gload_lds16(bsrc + (size_t)(i * 16) * DP, Bw0 + i * 512);

#define EXP_BODY(KB, BC, BN)                                                      \
    {                                                                             \
        asm volatile("s_waitcnt vmcnt(0)" ::: "memory");                          \
        __builtin_amdgcn_sched_barrier(0);                                        \
        const int kn_ = (KB) + KBLK;                                              \
        if (kn_ < DP) {                                                           \
            _Pragma("unroll")                                                     \
            for (int i = 0; i < 4; ++i)                                           \
                gload_lds16(bsrc + (size_t)(i * 16) * DP + kn_, (BN) + i * 512);  \
        }                                                                         \
        short8 af[4];                                                             \
        if (MODE) {                                                               \
            _Pragma("unroll")                                                     \
            for (int m = 0; m < 4; ++m)                                           \
                af[m] = *(const short8*)(pA[m] + (KB));                           \
        } else {                                                                  \
            const bool okg_ = ((KB) + lg * 8) < D_SZ;                             \
            _Pragma("unroll")                                                     \
            for (int m = 0; m < 4; ++m) {                                         \
                if (okg_) {                                                       \
                    float4 a0 = *(const float4*)(pAx[m] + (KB));                  \
                    float4 a1 = *(const float4*)(pAx[m] + (KB) + 4);              \
                    af[m][0] = (short)f2bf(a0.x); af[m][1] = (short)f2bf(a0.y);   \
                    af[m][2] = (short)f2bf(a0.z); af[m][3] = (short)f2bf(a0.w);   \
                    af[m][4] = (short)f2bf(a1.x); af[m][5] = (short)f2bf(a1.y);   \
                    af[m][6] = (short)f2bf(a1.z); af[m][7] = (short)f2bf(a1.w);   \
                } else {                                                          \
                    af[m] = (short8){0,0,0,0,0,0,0,0};                            \
                }                                                                 \
            }                                                                     \
        }                                                                         \
        short8 bfr[4];                                                            \
        _Pragma("unroll")                                                         \
        for (int n = 0; n < 4; ++n)                                               \
            bfr[n] = *(const short8*)&(BC)[(n * 16 + l15) * 32 + lg * 8];         \
        _Pragma("unroll")                                                         \
        for (int m = 0; m < 4; ++m)                                               \
            _Pragma("unroll")                                                     \
            for (int n = 0; n < 4; ++n)                                           \
                acc[m * 4 + n] = __builtin_amdgcn_mfma_f32_16x16x32_bf16(         \
                    af[m], bfr[n], acc[m * 4 + n], 0, 0, 0);                      \
    }

#pragma unroll 1
    for (int kb = 0; kb < DP; kb += 2 * KBLK) {
        EXP_BODY(kb,        Bw0, Bw1)
        EXP_BODY(kb + KBLK, Bw1, Bw0)
    }
#undef EXP_BODY

    // ---- epilogue: +b1, LN stats ----
    const float* b1e = b1    + (size_t)e * H_SZ;
    const float* gme = gamma + (size_t)e * H_SZ;
    const float* bte = beta  + (size_t)e * H_SZ;
    const float* w2e = W2    + (size_t)e * H_SZ;     // O==1

    float b1v[4];
#pragma unroll
    for (int n = 0; n < 4; ++n) b1v[n] = b1e[bn0 + n * 16 + l15];

#pragma unroll
    for (int m = 0; m < 4; ++m) {
        float s[4], q[4];
#pragma unroll
        for (int j = 0; j < 4; ++j) {
            float sv = 0.f, qv = 0.f;
#pragma unroll
            for (int n = 0; n < 4; ++n) {
                const float v = acc[m * 4 + n][j] + b1v[n];
                acc[m * 4 + n][j] = v;
                sv += v; qv += v * v;
            }
            s[j] = sv; q[j] = qv;
        }
#pragma unroll
        for (int j = 0; j < 4; ++j) {
#pragma unroll
            for (int d = 1; d < 16; d <<= 1) {
                s[j] += __shfl_xor(s[j], d);
                q[j] += __shfl_xor(q[j], d);
            }
        }
        if (l15 == 0) {
#pragma unroll
            for (int j = 0; j < 4; ++j) {
                const int row = m * 16 + lg * 4 + j;
                red[w][row][0] = s[j]; red[w][row][1] = q[j];
            }
        }
    }
    __syncthreads();

    if (t < BM) {
        float s = 0.f, q = 0.f;
#pragma unroll
        for (int ww = 0; ww < 16; ++ww) { s += red[ww][t][0]; q += red[ww][t][1]; }
        const float mean = s * (1.f / H_SZ);
        const float var  = q * (1.f / H_SZ) - mean * mean;
        ln_m[t] = mean;
        ln_r[t] = 1.f / sqrtf(var + LN_EPS);
    }
    __syncthreads();

    float gmv[4], btv[4], w2v[4];
#pragma unroll
    for (int n = 0; n < 4; ++n) {
        const int col = bn0 + n * 16 + l15;
        gmv[n] = gme[col]; btv[n] = bte[col]; w2v[n] = w2e[col];
    }
#pragma unroll
    for (int m = 0; m < 4; ++m) {
        float p[4];
#pragma unroll
        for (int j = 0; j < 4; ++j) {
            const int row = m * 16 + lg * 4 + j;
            const float mm = ln_m[row], rr = ln_r[row];
            float pv = 0.f;
#pragma unroll
            for (int n = 0; n < 4; ++n) {
                float h = (acc[m * 4 + n][j] - mm) * rr * gmv[n] + btv[n];
                h = fmaxf(h, 0.f);
                pv += h * w2v[n];
            }
            p[j] = pv;
        }
#pragma unroll
        for (int j = 0; j < 4; ++j)
#pragma unroll
            for (int d = 1; d < 16; d <<= 1) p[j] += __shfl_xor(p[j], d);
        if (l15 == 0) {
#pragma unroll
            for (int j = 0; j < 4; ++j) red[w][m * 16 + lg * 4 + j][0] = p[j];
        }
    }
    __syncthreads();

    if (t < BM && srow[t] >= 0) {
        float z = b2[e];
#pragma unroll
        for (int ww = 0; ww < 16; ++ww) z += red[ww][t][0];
        const float o = 1.f / (1.f + expf(-z));
        atomicAdd(&y[srow[t]], sgate[t] * o);
    }
}

// -------------------------------------------------------------- launcher ----
extern "C" void kernel_launch(void* const* d_in, const int* in_sizes, int n_in,
                              void* d_out, int out_size, void* d_ws, size_t ws_size,
                              hipStream_t stream)
{
    const float* x     = (const float*)d_in[0];
    const float* wg    = (const float*)d_in[1];
    const float* W1    = (const float*)d_in[2];
    const float* b1    = (const float*)d_in[3];
    const float* gamma = (const float*)d_in[4];
    const float* beta  = (const float*)d_in[5];
    const float* W2    = (const float*)d_in[6];
    const float* b2    = (const float*)d_in[7];
    float* y = (float*)d_out;

    char* ws = (char*)d_ws;
    int*   bucket_row  = (int*)ws;
    float* bucket_gate = (float*)(ws + (size_t)E_SZ * B_SZ * 4);
    const size_t base  = (size_t)E_SZ * B_SZ * 8;           // 4 MiB
    int*   cnt  = (int*)(ws + base);
    float* imp  = (float*)(ws + base + 64);
    int*   load = (int*)(ws + base + 128);
    unsigned short* Wp = (unsigned short*)(ws + base + 1024);
    const size_t WPB = (size_t)E_SZ * H_SZ * DP * 2;        // ~38 MiB

    // xb after Wp, 256-aligned; only used if ws_size is large enough
    size_t off_xb = base + 1024 + WPB;
    off_xb = (off_xb + 255) & ~(size_t)255;
    const size_t need = off_xb + (size_t)B_SZ * D_SZ * 2 + 256;
    const bool use_xb = (ws_size >= need);
    unsigned short* xb = use_xb ? (unsigned short*)(ws + off_xb) : nullptr;

    // gate scratch ALIASES the Wp region (gate kernels run before pack_w1)
    char* g = ws + base + 1024;
    unsigned*       tk_pack = (unsigned*)g;
    float*          gates4  = (float*)(g + (size_t)B_SZ * 4);
    unsigned short* lpos4   = (unsigned short*)(g + (size_t)B_SZ * 20);
    unsigned*       hist_g  = (unsigned*)(g + (size_t)B_SZ * 28);
    float*          bimp_g  = (float*)(g + (size_t)B_SZ * 28 + NBG * E_SZ * 4);
    unsigned*       base_g  = (unsigned*)(g + (size_t)B_SZ * 28 + NBG * E_SZ * 8);

    hipMemsetAsync(d_out, 0, (size_t)B_SZ * sizeof(float), stream);   // y = 0

    gate_a<<<NBG, 256, 0, stream>>>(x, wg, xb, tk_pack, gates4, lpos4, hist_g, bimp_g);
    gate_b<<<1, 1024, 0, stream>>>(hist_g, bimp_g, base_g, cnt, imp, load, y + B_SZ);
    gate_c<<<NBG, 256, 0, stream>>>(tk_pack, gates4, lpos4, base_g, bucket_row, bucket_gate);
    pack_w1<<<dim3(DP / 32, H_SZ / 32, E_SZ), 256, 0, stream>>>(W1, Wp);
    if (use_xb)
        expert_kernel<1><<<dim3(B_SZ / BM, E_SZ), 1024, 0, stream>>>(
            x, xb, Wp, b1, gamma, beta, W2, b2, bucket_row, bucket_gate, cnt, y);
    else
        expert_kernel<0><<<dim3(B_SZ / BM, E_SZ), 1024, 0, stream>>>(
            x, nullptr, Wp, b1, gamma, beta, W2, b2, bucket_row, bucket_gate, cnt, y);
}